// Round 11
// baseline (273.724 us; speedup 1.0000x reference)
//
#include <hip/hip_runtime.h>

// MultiHeadedAttention: B=2, S=2048, D=1024, H=16, DH=64. fp32 in/out.
// R11: R10 +
//  - attn XCD swizzle: bh = bid&31 so all 16 blocks of a bh share bid%8
//    (same XCD L2) -> KV refetch drops (FETCH was stuck at 70MB).
//  - attn VALU trim: log2e folded into q-scale (exp2f, no v_mul), P packed
//    via +0x8000 bias + v_perm_b32 (1.5 ops/elem vs ~4.5).
//  - gemm_qkv: BK=64 staging (8 async16/round, 32 MFMA/round, half drains).
//  - gemm_final: 64x128 tile, 512 blocks = 2/CU (was 1/CU).
#define B_ 2
#define S_ 2048
#define D_ 1024
#define H_ 16
#define DH_ 64

typedef float f32x4 __attribute__((ext_vector_type(4)));
typedef short s16x8 __attribute__((ext_vector_type(8)));
typedef __bf16 bf16x8 __attribute__((ext_vector_type(8)));
typedef unsigned int uint;

// q scale: (1/8) * log2(e) -- attn uses exp2, exp2(x*log2e) == e^x
#define QSCALE 0.18033688011112042f

// ---- MFMA wrapper: tolerate either builtin signature (short8 or bf16x8) ----
template <typename T>
static __device__ auto mfma_sel(T a, T b, f32x4 c, int)
    -> decltype(__builtin_amdgcn_mfma_f32_16x16x32_bf16(a, b, c, 0, 0, 0)) {
  return __builtin_amdgcn_mfma_f32_16x16x32_bf16(a, b, c, 0, 0, 0);
}
template <typename T>
static __device__ f32x4 mfma_sel(T a, T b, f32x4 c, long) {
  return __builtin_amdgcn_mfma_f32_16x16x32_bf16(
      __builtin_bit_cast(bf16x8, a), __builtin_bit_cast(bf16x8, b), c, 0, 0, 0);
}
static __device__ __forceinline__ f32x4 mfma_bf16(s16x8 a, s16x8 b, f32x4 c) {
  return mfma_sel(a, b, c, 0);
}

static __device__ __forceinline__ short f2bf(float f) {
  unsigned u = __float_as_uint(f);
  u += 0x7fffu + ((u >> 16) & 1u);
  return (short)(u >> 16);
}

// ---- async 16B global -> LDS (per-lane GLOBAL addr ok; LDS side = base+lane*16)
static __device__ __forceinline__ void async16(const short* g, short* l) {
  __builtin_amdgcn_global_load_lds(
      (const __attribute__((address_space(1))) unsigned int*)g,
      (__attribute__((address_space(3))) unsigned int*)l, 16, 0, 0);
}

// ---- mask dtype probe: 0 = byte-bool, 1 = int32 0/1, 2 = fp32 0.0/1.0 ----
__global__ void detect_mask_kernel(const uint* __restrict__ m,
                                   int* __restrict__ flag) {
  int lane = threadIdx.x;
  bool gt1 = false, notf = false;
  for (int i = 0; i < 16; ++i) {
    uint v = m[lane * 16 + i];
    if (v > 1u) gt1 = true;
    if (v != 0u && v != 0x3F800000u) notf = true;
  }
  unsigned long long b1 = __ballot(gt1);
  unsigned long long b2 = __ballot(notf);
  if (lane == 0) {
    int f;
    if (b1 == 0ull) f = 1;
    else if (b2 == 0ull) f = 2;
    else f = 0;
    *flag = f;
  }
}

// ---- mask -> bitmask. bmT[b][kt][q] bit i = (mask[b][q][kt*32+i] != 0) ----
__global__ __launch_bounds__(256) void build_bitmask_kernel(
    const void* __restrict__ mask, const int* __restrict__ flag,
    uint* __restrict__ bmT) {
  int w = blockIdx.x * 256 + threadIdx.x;
  int b = w >> 17;
  int rem = w & 131071;
  int q = rem >> 6;
  int kt = rem & 63;
  int mty = *flag;
  uint bits = 0;
  if (mty == 0) {
    const uint* p = (const uint*)((const unsigned char*)mask +
                                  ((size_t)b * S_ + q) * S_ + (size_t)kt * 32);
#pragma unroll
    for (int i = 0; i < 8; ++i) {
      uint v = p[i];
#pragma unroll
      for (int j = 0; j < 4; ++j)
        if ((v >> (8 * j)) & 0xffu) bits |= 1u << (i * 4 + j);
    }
  } else {
    const uint* p = (const uint*)mask + ((size_t)b * S_ + q) * S_ + kt * 32;
#pragma unroll
    for (int i = 0; i < 32; ++i)
      if (p[i]) bits |= 1u << i;
  }
  bmT[((size_t)b * (S_ / 32) + kt) * S_ + q] = bits;
}

// ---- fp32 -> bf16 convert into FRAGMENT-ORDER layout (query + Wq/Wk/Wv) ----
__global__ __launch_bounds__(256) void convert_kernel(
    const float* __restrict__ q, const float* __restrict__ wq,
    const float* __restrict__ wk, const float* __restrict__ wv,
    short* __restrict__ qbf, short* __restrict__ wqkv) {
  int bid = blockIdx.x;
  int t = threadIdx.x;
  const float* src;
  short* dst;
  int rowbase, seg;
  if (bid < 2048)      { src = q;  dst = qbf;  rowbase = bid * 2;          seg = -1; }
  else if (bid < 2560) { src = wq; dst = wqkv; rowbase = (bid - 2048) * 2; seg = 0; }
  else if (bid < 3072) { src = wk; dst = wqkv; rowbase = (bid - 2560) * 2; seg = 1; }
  else                 { src = wv; dst = wqkv; rowbase = (bid - 3072) * 2; seg = 2; }
  int rl = rowbase + (t >> 7);
  int k = (t & 127) * 8;
  const float* s8 = src + (size_t)rl * 1024 + k;
  f32x4 a = *(const f32x4*)s8;
  f32x4 b = *(const f32x4*)(s8 + 4);
  s16x8 r;
  r[0] = f2bf(a[0]); r[1] = f2bf(a[1]); r[2] = f2bf(a[2]); r[3] = f2bf(a[3]);
  r[4] = f2bf(b[0]); r[5] = f2bf(b[1]); r[6] = f2bf(b[2]); r[7] = f2bf(b[3]);
  int grow = (seg < 0) ? rl : (seg * 1024 + rl);
  size_t chunk = ((size_t)(grow >> 4) * 32 + (k >> 5)) * 64 +
                 ((k >> 3) & 3) * 16 + (grow & 15);
  *(s16x8*)(dst + chunk * 8) = r;
}

// ---- fp32 -> bf16 row-major convert for Wo (runs AFTER attn, into q_ws) ----
__global__ __launch_bounds__(256) void convert_wo_kernel(
    const float* __restrict__ wo, short* __restrict__ wob) {
  size_t i = ((size_t)blockIdx.x * 256 + threadIdx.x) * 8;
  f32x4 a = *(const f32x4*)(wo + i);
  f32x4 b = *(const f32x4*)(wo + i + 4);
  s16x8 r;
  r[0] = f2bf(a[0]); r[1] = f2bf(a[1]); r[2] = f2bf(a[2]); r[3] = f2bf(a[3]);
  r[4] = f2bf(b[0]); r[5] = f2bf(b[1]); r[6] = f2bf(b[2]); r[7] = f2bf(b[3]);
  *(s16x8*)(wob + i) = r;
}

// ---- fused QKV GEMM, BK=64 staged: C[4096,3072] = qbf @ wqkv^T -------------
__global__ __launch_bounds__(256) void gemm_qkv_kernel(
    const short* __restrict__ A, const short* __restrict__ Bt,
    const float* __restrict__ bq, const float* __restrict__ bk,
    const float* __restrict__ bv, short* __restrict__ q_ws,
    short* __restrict__ KF, short* __restrict__ VF) {
  __shared__ short lds[16384];  // A [0:8192), B [8192:16384); slot=(grp*2+t)
  const int tid = threadIdx.x;
  const int lane = tid & 63;
  const int wave = tid >> 6;
  const int l16 = lane & 15;
  const int quad = lane >> 4;
  const int mb0 = blockIdx.x * 8;
  const int nb0 = blockIdx.y * 8;
  const int m0 = blockIdx.x * 128 + (wave >> 1) * 64;
  const int n0 = blockIdx.y * 128 + (wave & 1) * 64;
  const int g = tid >> 6, c = tid & 63;

  f32x4 acc[4][4];
#pragma unroll
  for (int i = 0; i < 4; ++i)
#pragma unroll
    for (int j = 0; j < 4; ++j) acc[i][j] = (f32x4){0.f, 0.f, 0.f, 0.f};

  for (int kb2 = 0; kb2 < 16; ++kb2) {
#pragma unroll
    for (int t = 0; t < 2; ++t) {
      int kb = kb2 * 2 + t;
      async16(A + (((size_t)(mb0 + g) * 32 + kb) * 64 + c) * 8,
              lds + ((g * 2 + t) * 64 + c) * 8);
      async16(A + (((size_t)(mb0 + g + 4) * 32 + kb) * 64 + c) * 8,
              lds + (((g + 4) * 2 + t) * 64 + c) * 8);
      async16(Bt + (((size_t)(nb0 + g) * 32 + kb) * 64 + c) * 8,
              lds + 8192 + ((g * 2 + t) * 64 + c) * 8);
      async16(Bt + (((size_t)(nb0 + g + 4) * 32 + kb) * 64 + c) * 8,
              lds + 8192 + (((g + 4) * 2 + t) * 64 + c) * 8);
    }
    __syncthreads();
#pragma unroll
    for (int t = 0; t < 2; ++t) {
      s16x8 a[4], b[4];
#pragma unroll
      for (int i = 0; i < 4; ++i)
        a[i] = *(const s16x8*)(lds +
                               ((((wave >> 1) * 4 + i) * 2 + t) * 64 + lane) * 8);
#pragma unroll
      for (int j = 0; j < 4; ++j)
        b[j] = *(const s16x8*)(lds + 8192 +
                               ((((wave & 1) * 4 + j) * 2 + t) * 64 + lane) * 8);
#pragma unroll
      for (int i = 0; i < 4; ++i)
#pragma unroll
        for (int j = 0; j < 4; ++j) acc[i][j] = mfma_bf16(a[i], b[j], acc[i][j]);
    }
    __syncthreads();
  }

#pragma unroll
  for (int i = 0; i < 4; ++i) {
#pragma unroll
    for (int j = 0; j < 4; ++j) {
#pragma unroll
      for (int r = 0; r < 4; ++r) {
        int m = m0 + i * 16 + quad * 4 + r;
        int n = n0 + j * 16 + l16;
        int seg = n >> 10, nl = n & 1023;
        float bias = (seg == 0) ? bq[nl] : ((seg == 1) ? bk[nl] : bv[nl]);
        float v = acc[i][j][r] + bias;
        if (seg == 0) v *= QSCALE;  // 1/8 * log2e (attn uses exp2)
        int bb = m >> 11, s = m & (S_ - 1);
        int hh = nl >> 6, dh = nl & 63;
        int bh = bb * H_ + hh;
        short bv16 = f2bf(v);
        if (seg == 0) {
          q_ws[((size_t)bh * S_ + s) * DH_ + dh] = bv16;
        } else if (seg == 1) {
          int kt = s >> 5, r5 = s & 31;
          int kkb = r5 >> 4, kl16 = r5 & 15;
          int kf = dh >> 5, qd = (dh >> 3) & 3, e = dh & 7;
          KF[(size_t)bh * 131072 +
             ((size_t)kt * 256 + (kkb * 2 + kf) * 64 + qd * 16 + kl16) * 8 + e] = bv16;
        } else {
          int kt = s >> 5, ko = s & 31;
          int hi = ko >> 4, qd = (ko >> 2) & 3, j4 = ko & 3;
          int nb = dh >> 4, vl16 = dh & 15, e = hi * 4 + j4;
          VF[(size_t)bh * 131072 +
             ((size_t)kt * 256 + nb * 64 + qd * 16 + vl16) * 8 + e] = bv16;
        }
      }
    }
  }
}

// ---- attention: 512 blocks x 8 waves, BK=64; XCD-local bh mapping ----------
__global__ void attn_kernel(
    const short* __restrict__ Q, const short* __restrict__ KF,
    const short* __restrict__ VF, const uint* __restrict__ bmT,
    short* __restrict__ ctx_out) {
  __shared__ short lds[8192];  // K 64x64 [0:4096), V 64x64 [4096:8192) shorts
  const int tid = threadIdx.x;           // [0,512)
  const int lane = tid & 63;
  const int wave = tid >> 6;             // [0,8)
  const int l16 = lane & 15;
  const int quad = lane >> 4;
  const int bid = blockIdx.x;            // [0,512)
  const int bh = bid & 31;    // XCD swizzle: same bh -> same bid%8 -> same XCD
  const int qt128 = bid >> 5;
  const int b = bh >> 4;
  const int h = bh & 15;
  const int qbase = qt128 * 128 + wave * 16;

  const short* Qh = Q + (size_t)bh * S_ * DH_;
  const short* KFb = KF + (size_t)bh * 131072;
  const short* VFb = VF + (size_t)bh * 131072;
  const uint* bmb = bmT + (size_t)b * (S_ / 32) * S_;

  s16x8 qf[2];
#pragma unroll
  for (int kf = 0; kf < 2; ++kf)
    qf[kf] = *(const s16x8*)(Qh + (size_t)(qbase + l16) * DH_ + kf * 32 + quad * 8);

  f32x4 ctx[4];
#pragma unroll
  for (int nb = 0; nb < 4; ++nb) ctx[nb] = (f32x4){0.f, 0.f, 0.f, 0.f};
  float ls = 0.f;

  for (int kt2 = 0; kt2 < S_ / 64; ++kt2) {
    async16(KFb + (size_t)kt2 * 4096 + tid * 8, lds + tid * 8);
    async16(VFb + (size_t)kt2 * 4096 + tid * 8, lds + 4096 + tid * 8);
    uint w[2];
    w[0] = bmb[(size_t)(2 * kt2) * S_ + qbase + l16];
    w[1] = bmb[(size_t)(2 * kt2 + 1) * S_ + qbase + l16];
    __syncthreads();

#pragma unroll
    for (int kbt = 0; kbt < 2; ++kbt) {
      s16x8 ka[2][2];
#pragma unroll
      for (int kb = 0; kb < 2; ++kb)
#pragma unroll
        for (int kf = 0; kf < 2; ++kf)
          ka[kb][kf] =
              *(const s16x8*)(lds + kbt * 2048 + ((kb * 2 + kf) * 64 + lane) * 8);

      // scores^T: C row = key(quad*4+r), col = q(l16). q pre-scaled by log2e/8.
      f32x4 sc[2];
#pragma unroll
      for (int kb = 0; kb < 2; ++kb) {
        f32x4 t = mfma_bf16(ka[kb][0], qf[0], (f32x4){0.f, 0.f, 0.f, 0.f});
        sc[kb] = mfma_bf16(ka[kb][1], qf[1], t);
      }

      // exp2 + mask; pack to PV A-operand via +0x8000 bias + v_perm_b32
      uint pk[4];
      float sum = 0.f;
#pragma unroll
      for (int kb = 0; kb < 2; ++kb) {
        uint t[4];
#pragma unroll
        for (int r = 0; r < 4; ++r) {
          int bit = (w[kbt] >> (kb * 16 + quad * 4 + r)) & 1;
          float p = bit ? 0.f : exp2f(sc[kb][r]);
          sum += p;
          t[r] = __float_as_uint(p) + 0x8000u;
        }
        pk[kb * 2 + 0] = __builtin_amdgcn_perm(t[1], t[0], 0x07060302u);
        pk[kb * 2 + 1] = __builtin_amdgcn_perm(t[3], t[2], 0x07060302u);
      }
      s16x8 pa = __builtin_bit_cast(s16x8, pk);
      ls += sum;

#pragma unroll
      for (int nb = 0; nb < 4; ++nb) {
        s16x8 vb =
            *(const s16x8*)(lds + 4096 + kbt * 2048 + (nb * 64 + lane) * 8);
        ctx[nb] = mfma_bf16(pa, vb, ctx[nb]);
      }
    }
    __syncthreads();
  }

  ls += __shfl_xor(ls, 16);
  ls += __shfl_xor(ls, 32);

#pragma unroll
  for (int r = 0; r < 4; ++r) {
    float lr = __shfl(ls, quad * 4 + r);
    float inv = 1.f / lr;
    int srow = qbase + quad * 4 + r;
#pragma unroll
    for (int nb = 0; nb < 4; ++nb) {
      int col = h * DH_ + nb * 16 + l16;
      ctx_out[(size_t)(b * S_ + srow) * D_ + col] = f2bf(ctx[nb][r] * inv);
    }
  }
}

// ---- final GEMM, 64x128 tile staged: out fp32 = ctx_bf16 @ Wo_bf16^T + bo --
__global__ __launch_bounds__(256) void gemm_final_kernel(
    const short* __restrict__ A, const short* __restrict__ Bt,
    const float* __restrict__ bias, float* __restrict__ out) {
  __shared__ short lds[6144];  // A 64x32 [0:2048), B 128x32 [2048:6144)
  const int tid = threadIdx.x;
  const int lane = tid & 63;
  const int wave = tid >> 6;
  const int l16 = lane & 15;
  const int quad = lane >> 4;
  const int m0 = blockIdx.x * 64;
  const int n0 = blockIdx.y * 128;
  const int g = tid >> 6, c = tid & 63;
  const int r15 = c & 15, qd = c >> 4;

  f32x4 acc[2][4];
#pragma unroll
  for (int i = 0; i < 2; ++i)
#pragma unroll
    for (int j = 0; j < 4; ++j) acc[i][j] = (f32x4){0.f, 0.f, 0.f, 0.f};

  for (int k0 = 0; k0 < 1024; k0 += 32) {
    async16(A + (size_t)(m0 + g * 16 + r15) * 1024 + k0 + qd * 8, lds + tid * 8);
    async16(Bt + (size_t)(n0 + g * 16 + r15) * 1024 + k0 + qd * 8,
            lds + 2048 + (g * 64 + c) * 8);
    async16(Bt + (size_t)(n0 + (g + 4) * 16 + r15) * 1024 + k0 + qd * 8,
            lds + 2048 + ((g + 4) * 64 + c) * 8);
    __syncthreads();
    s16x8 a[2], b[4];
#pragma unroll
    for (int i = 0; i < 2; ++i)
      a[i] = *(const s16x8*)(lds + (((wave >> 1) * 2 + i) * 64 + lane) * 8);
#pragma unroll
    for (int j = 0; j < 4; ++j)
      b[j] = *(const s16x8*)(lds + 2048 + (((wave & 1) * 4 + j) * 64 + lane) * 8);
#pragma unroll
    for (int i = 0; i < 2; ++i)
#pragma unroll
      for (int j = 0; j < 4; ++j) acc[i][j] = mfma_bf16(a[i], b[j], acc[i][j]);
    __syncthreads();
  }

  const int mw = m0 + (wave >> 1) * 32;
  const int nw = n0 + (wave & 1) * 64;
#pragma unroll
  for (int i = 0; i < 2; ++i)
#pragma unroll
    for (int j = 0; j < 4; ++j)
#pragma unroll
      for (int r = 0; r < 4; ++r) {
        int m = mw + i * 16 + quad * 4 + r;
        int n = nw + j * 16 + l16;
        out[(size_t)m * 1024 + n] = acc[i][j][r] + bias[n];
      }
}

extern "C" void kernel_launch(void* const* d_in, const int* in_sizes, int n_in,
                              void* d_out, int out_size, void* d_ws,
                              size_t ws_size, hipStream_t stream) {
  const float* query = (const float*)d_in[0];
  const void* mask = d_in[1];
  const float* Wq = (const float*)d_in[2];
  const float* bq = (const float*)d_in[3];
  const float* Wk = (const float*)d_in[4];
  const float* bk = (const float*)d_in[5];
  const float* Wv = (const float*)d_in[6];
  const float* bv = (const float*)d_in[7];
  const float* Wo = (const float*)d_in[8];
  const float* bo = (const float*)d_in[9];

  const size_t NE = (size_t)B_ * S_ * D_;  // 4194304
  short* ws_s = (short*)d_ws;
  short* q_ws = ws_s;             // [B,H,S,DH] bf16 row-major (8 MB)
  short* KF = ws_s + NE;          // K fragment-order (8 MB)
  short* VF = ws_s + 2 * NE;      // V fragment-order, PV-permuted (8 MB)
  short* ctx_ws = ws_s + 3 * NE;  // [B,S,D] bf16 row-major (8 MB)
  short* wo_bf = ws_s;            // Wo bf16 (2 MB) -- aliases q_ws, written
                                  // only after attn (q_ws dead then)
  // scratch inside d_out (all dead before the final GEMM runs):
  short* qbf = (short*)d_out;          // [0:8M)  query bf16, fragment order
  short* wqkv = qbf + NE;              // [8:14M) Wq|Wk|Wv bf16, fragment order
  uint* bmT = (uint*)(wqkv + 3145728); // [14:15M) bitmask
  int* flag = (int*)(bmT + 262144);

  detect_mask_kernel<<<1, 64, 0, stream>>>((const uint*)mask, flag);
  build_bitmask_kernel<<<1024, 256, 0, stream>>>(mask, flag, bmT);
  convert_kernel<<<3584, 256, 0, stream>>>(query, Wq, Wk, Wv, qbf, wqkv);

  gemm_qkv_kernel<<<dim3(32, 24), 256, 0, stream>>>(qbf, wqkv, bq, bk, bv,
                                                    q_ws, KF, VF);

  attn_kernel<<<512, 512, 0, stream>>>(q_ws, KF, VF, bmT, ctx_ws);

  convert_wo_kernel<<<512, 256, 0, stream>>>(Wo, wo_bf);

  gemm_final_kernel<<<dim3(64, 8), 256, 0, stream>>>(ctx_ws, wo_bf, bo,
                                                     (float*)d_out);
}

// Round 12
// 259.440 us; speedup vs baseline: 1.0551x; 1.0551x over previous
//
#include <hip/hip_runtime.h>

// MultiHeadedAttention: B=2, S=2048, D=1024, H=16, DH=64. fp32 in/out.
// R12: base = R10 (best: 252us). Reverted R11's XCD swizzle (cut FETCH 4x but
// slowed attn 17% -- HBM was never binding) and perm-pack and qkv-BK64.
// Kept: log2e folded into q-scale (attn uses exp2f). New in attn:
//  - BK=128: 4 key-tiles per barrier (16 drains vs 32), 32KB LDS.
//  - l-sum via ones-column MFMA: denominator computed in the matrix pipe;
//    removes 16 serial v_adds/kbt + both epilogue shfls.
#define B_ 2
#define S_ 2048
#define D_ 1024
#define H_ 16
#define DH_ 64

typedef float f32x4 __attribute__((ext_vector_type(4)));
typedef short s16x8 __attribute__((ext_vector_type(8)));
typedef __bf16 bf16x8 __attribute__((ext_vector_type(8)));
typedef unsigned int uint;

// q scale: (1/8) * log2(e) -- attn uses exp2, exp2(x*log2e) == e^x
#define QSCALE 0.18033688011112042f

// ---- MFMA wrapper: tolerate either builtin signature (short8 or bf16x8) ----
template <typename T>
static __device__ auto mfma_sel(T a, T b, f32x4 c, int)
    -> decltype(__builtin_amdgcn_mfma_f32_16x16x32_bf16(a, b, c, 0, 0, 0)) {
  return __builtin_amdgcn_mfma_f32_16x16x32_bf16(a, b, c, 0, 0, 0);
}
template <typename T>
static __device__ f32x4 mfma_sel(T a, T b, f32x4 c, long) {
  return __builtin_amdgcn_mfma_f32_16x16x32_bf16(
      __builtin_bit_cast(bf16x8, a), __builtin_bit_cast(bf16x8, b), c, 0, 0, 0);
}
static __device__ __forceinline__ f32x4 mfma_bf16(s16x8 a, s16x8 b, f32x4 c) {
  return mfma_sel(a, b, c, 0);
}

static __device__ __forceinline__ short f2bf(float f) {
  unsigned u = __float_as_uint(f);
  u += 0x7fffu + ((u >> 16) & 1u);
  return (short)(u >> 16);
}

// ---- async 16B global -> LDS (per-lane GLOBAL addr ok; LDS side = base+lane*16)
static __device__ __forceinline__ void async16(const short* g, short* l) {
  __builtin_amdgcn_global_load_lds(
      (const __attribute__((address_space(1))) unsigned int*)g,
      (__attribute__((address_space(3))) unsigned int*)l, 16, 0, 0);
}

// ---- mask dtype probe: 0 = byte-bool, 1 = int32 0/1, 2 = fp32 0.0/1.0 ----
__global__ void detect_mask_kernel(const uint* __restrict__ m,
                                   int* __restrict__ flag) {
  int lane = threadIdx.x;
  bool gt1 = false, notf = false;
  for (int i = 0; i < 16; ++i) {
    uint v = m[lane * 16 + i];
    if (v > 1u) gt1 = true;
    if (v != 0u && v != 0x3F800000u) notf = true;
  }
  unsigned long long b1 = __ballot(gt1);
  unsigned long long b2 = __ballot(notf);
  if (lane == 0) {
    int f;
    if (b1 == 0ull) f = 1;
    else if (b2 == 0ull) f = 2;
    else f = 0;
    *flag = f;
  }
}

// ---- mask -> bitmask. bmT[b][kt][q] bit i = (mask[b][q][kt*32+i] != 0) ----
__global__ __launch_bounds__(256) void build_bitmask_kernel(
    const void* __restrict__ mask, const int* __restrict__ flag,
    uint* __restrict__ bmT) {
  int w = blockIdx.x * 256 + threadIdx.x;
  int b = w >> 17;
  int rem = w & 131071;
  int q = rem >> 6;
  int kt = rem & 63;
  int mty = *flag;
  uint bits = 0;
  if (mty == 0) {
    const uint* p = (const uint*)((const unsigned char*)mask +
                                  ((size_t)b * S_ + q) * S_ + (size_t)kt * 32);
#pragma unroll
    for (int i = 0; i < 8; ++i) {
      uint v = p[i];
#pragma unroll
      for (int j = 0; j < 4; ++j)
        if ((v >> (8 * j)) & 0xffu) bits |= 1u << (i * 4 + j);
    }
  } else {
    const uint* p = (const uint*)mask + ((size_t)b * S_ + q) * S_ + kt * 32;
#pragma unroll
    for (int i = 0; i < 32; ++i)
      if (p[i]) bits |= 1u << i;
  }
  bmT[((size_t)b * (S_ / 32) + kt) * S_ + q] = bits;
}

// ---- fp32 -> bf16 convert into FRAGMENT-ORDER layout (query + Wq/Wk/Wv) ----
__global__ __launch_bounds__(256) void convert_kernel(
    const float* __restrict__ q, const float* __restrict__ wq,
    const float* __restrict__ wk, const float* __restrict__ wv,
    short* __restrict__ qbf, short* __restrict__ wqkv) {
  int bid = blockIdx.x;
  int t = threadIdx.x;
  const float* src;
  short* dst;
  int rowbase, seg;
  if (bid < 2048)      { src = q;  dst = qbf;  rowbase = bid * 2;          seg = -1; }
  else if (bid < 2560) { src = wq; dst = wqkv; rowbase = (bid - 2048) * 2; seg = 0; }
  else if (bid < 3072) { src = wk; dst = wqkv; rowbase = (bid - 2560) * 2; seg = 1; }
  else                 { src = wv; dst = wqkv; rowbase = (bid - 3072) * 2; seg = 2; }
  int rl = rowbase + (t >> 7);
  int k = (t & 127) * 8;
  const float* s8 = src + (size_t)rl * 1024 + k;
  f32x4 a = *(const f32x4*)s8;
  f32x4 b = *(const f32x4*)(s8 + 4);
  s16x8 r;
  r[0] = f2bf(a[0]); r[1] = f2bf(a[1]); r[2] = f2bf(a[2]); r[3] = f2bf(a[3]);
  r[4] = f2bf(b[0]); r[5] = f2bf(b[1]); r[6] = f2bf(b[2]); r[7] = f2bf(b[3]);
  int grow = (seg < 0) ? rl : (seg * 1024 + rl);
  size_t chunk = ((size_t)(grow >> 4) * 32 + (k >> 5)) * 64 +
                 ((k >> 3) & 3) * 16 + (grow & 15);
  *(s16x8*)(dst + chunk * 8) = r;
}

// ---- fp32 -> bf16 row-major convert for Wo (runs AFTER attn, into q_ws) ----
__global__ __launch_bounds__(256) void convert_wo_kernel(
    const float* __restrict__ wo, short* __restrict__ wob) {
  size_t i = ((size_t)blockIdx.x * 256 + threadIdx.x) * 8;
  f32x4 a = *(const f32x4*)(wo + i);
  f32x4 b = *(const f32x4*)(wo + i + 4);
  s16x8 r;
  r[0] = f2bf(a[0]); r[1] = f2bf(a[1]); r[2] = f2bf(a[2]); r[3] = f2bf(a[3]);
  r[4] = f2bf(b[0]); r[5] = f2bf(b[1]); r[6] = f2bf(b[2]); r[7] = f2bf(b[3]);
  *(s16x8*)(wob + i) = r;
}

// ---- fused QKV GEMM, BK=32 staged (R10-proven): C[4096,3072] = qbf @ wqkv^T -
__global__ __launch_bounds__(256) void gemm_qkv_kernel(
    const short* __restrict__ A, const short* __restrict__ Bt,
    const float* __restrict__ bq, const float* __restrict__ bk,
    const float* __restrict__ bv, short* __restrict__ q_ws,
    short* __restrict__ KF, short* __restrict__ VF) {
  __shared__ short lds[8192];
  const int tid = threadIdx.x;
  const int lane = tid & 63;
  const int wave = tid >> 6;
  const int l16 = lane & 15;
  const int quad = lane >> 4;
  const int mb0 = blockIdx.x * 8;
  const int nb0 = blockIdx.y * 8;
  const int m0 = blockIdx.x * 128 + (wave >> 1) * 64;
  const int n0 = blockIdx.y * 128 + (wave & 1) * 64;
  const int g = tid >> 6, c = tid & 63;

  f32x4 acc[4][4];
#pragma unroll
  for (int i = 0; i < 4; ++i)
#pragma unroll
    for (int j = 0; j < 4; ++j) acc[i][j] = (f32x4){0.f, 0.f, 0.f, 0.f};

  for (int kb = 0; kb < 32; ++kb) {
    async16(A + (((size_t)(mb0 + g) * 32 + kb) * 64 + c) * 8, lds + tid * 8);
    async16(A + (((size_t)(mb0 + g + 4) * 32 + kb) * 64 + c) * 8,
            lds + 2048 + tid * 8);
    async16(Bt + (((size_t)(nb0 + g) * 32 + kb) * 64 + c) * 8,
            lds + 4096 + tid * 8);
    async16(Bt + (((size_t)(nb0 + g + 4) * 32 + kb) * 64 + c) * 8,
            lds + 6144 + tid * 8);
    __syncthreads();
    s16x8 a[4], b[4];
#pragma unroll
    for (int i = 0; i < 4; ++i)
      a[i] = *(const s16x8*)(lds + (((wave >> 1) * 4 + i) * 64 + lane) * 8);
#pragma unroll
    for (int j = 0; j < 4; ++j)
      b[j] = *(const s16x8*)(lds + 4096 + (((wave & 1) * 4 + j) * 64 + lane) * 8);
#pragma unroll
    for (int i = 0; i < 4; ++i)
#pragma unroll
      for (int j = 0; j < 4; ++j) acc[i][j] = mfma_bf16(a[i], b[j], acc[i][j]);
    __syncthreads();
  }

#pragma unroll
  for (int i = 0; i < 4; ++i) {
#pragma unroll
    for (int j = 0; j < 4; ++j) {
#pragma unroll
      for (int r = 0; r < 4; ++r) {
        int m = m0 + i * 16 + quad * 4 + r;
        int n = n0 + j * 16 + l16;
        int seg = n >> 10, nl = n & 1023;
        float bias = (seg == 0) ? bq[nl] : ((seg == 1) ? bk[nl] : bv[nl]);
        float v = acc[i][j][r] + bias;
        if (seg == 0) v *= QSCALE;  // 1/8 * log2e (attn uses exp2)
        int bb = m >> 11, s = m & (S_ - 1);
        int hh = nl >> 6, dh = nl & 63;
        int bh = bb * H_ + hh;
        short bv16 = f2bf(v);
        if (seg == 0) {
          q_ws[((size_t)bh * S_ + s) * DH_ + dh] = bv16;
        } else if (seg == 1) {
          int kt = s >> 5, r5 = s & 31;
          int kkb = r5 >> 4, kl16 = r5 & 15;
          int kf = dh >> 5, qd = (dh >> 3) & 3, e = dh & 7;
          KF[(size_t)bh * 131072 +
             ((size_t)kt * 256 + (kkb * 2 + kf) * 64 + qd * 16 + kl16) * 8 + e] = bv16;
        } else {
          int kt = s >> 5, ko = s & 31;
          int hi = ko >> 4, qd = (ko >> 2) & 3, j4 = ko & 3;
          int nb = dh >> 4, vl16 = dh & 15, e = hi * 4 + j4;
          VF[(size_t)bh * 131072 +
             ((size_t)kt * 256 + nb * 64 + qd * 16 + vl16) * 8 + e] = bv16;
        }
      }
    }
  }
}

// ---- attention: 512 blocks x 8 waves, BK=128; ones-MFMA denominator --------
__global__ void attn_kernel(
    const short* __restrict__ Q, const short* __restrict__ KF,
    const short* __restrict__ VF, const uint* __restrict__ bmT,
    short* __restrict__ ctx_out) {
  __shared__ short lds[16384];  // K 128x64 [0:8192), V 128x64 [8192:16384)
  const int tid = threadIdx.x;           // [0,512)
  const int lane = tid & 63;
  const int wave = tid >> 6;             // [0,8)
  const int l16 = lane & 15;
  const int quad = lane >> 4;
  const int bid = blockIdx.x;            // [0,512)
  const int bh = bid >> 4;               // R10 mapping (no XCD swizzle)
  const int qt128 = bid & 15;
  const int b = bh >> 4;
  const int h = bh & 15;
  const int qbase = qt128 * 128 + wave * 16;

  const short* Qh = Q + (size_t)bh * S_ * DH_;
  const short* KFb = KF + (size_t)bh * 131072;
  const short* VFb = VF + (size_t)bh * 131072;
  const uint* bmb = bmT + (size_t)b * (S_ / 32) * S_;

  s16x8 qf[2];
#pragma unroll
  for (int kf = 0; kf < 2; ++kf)
    qf[kf] = *(const s16x8*)(Qh + (size_t)(qbase + l16) * DH_ + kf * 32 + quad * 8);

  s16x8 vones;
#pragma unroll
  for (int e = 0; e < 8; ++e) vones[e] = (short)0x3F80;  // bf16 1.0

  f32x4 ctx[4], ctx5;
#pragma unroll
  for (int nb = 0; nb < 4; ++nb) ctx[nb] = (f32x4){0.f, 0.f, 0.f, 0.f};
  ctx5 = (f32x4){0.f, 0.f, 0.f, 0.f};

  for (int kt4 = 0; kt4 < S_ / 128; ++kt4) {
    // stage 128 keys of K and V (16KB each side; 4 async16 per thread)
    async16(KFb + (size_t)kt4 * 8192 + tid * 8, lds + tid * 8);
    async16(KFb + (size_t)kt4 * 8192 + 4096 + tid * 8, lds + 4096 + tid * 8);
    async16(VFb + (size_t)kt4 * 8192 + tid * 8, lds + 8192 + tid * 8);
    async16(VFb + (size_t)kt4 * 8192 + 4096 + tid * 8, lds + 12288 + tid * 8);
    uint w[4];
#pragma unroll
    for (int t = 0; t < 4; ++t)
      w[t] = bmb[(size_t)(4 * kt4 + t) * S_ + qbase + l16];
    __syncthreads();

#pragma unroll
    for (int kbt = 0; kbt < 4; ++kbt) {
      s16x8 ka[2][2];
#pragma unroll
      for (int kb = 0; kb < 2; ++kb)
#pragma unroll
        for (int kf = 0; kf < 2; ++kf)
          ka[kb][kf] =
              *(const s16x8*)(lds + kbt * 2048 + ((kb * 2 + kf) * 64 + lane) * 8);

      // scores^T: C row = key(quad*4+r), col = q(l16). q pre-scaled by log2e/8.
      f32x4 sc[2];
#pragma unroll
      for (int kb = 0; kb < 2; ++kb) {
        f32x4 t = mfma_bf16(ka[kb][0], qf[0], (f32x4){0.f, 0.f, 0.f, 0.f});
        sc[kb] = mfma_bf16(ka[kb][1], qf[1], t);
      }

      // exp2 + mask + pack to PV A-operand (k_phys = (j>>2)*16+quad*4+(j&3))
      s16x8 pa;
#pragma unroll
      for (int kb = 0; kb < 2; ++kb)
#pragma unroll
        for (int r = 0; r < 4; ++r) {
          int bit = (w[kbt] >> (kb * 16 + quad * 4 + r)) & 1;
          float p = bit ? 0.f : exp2f(sc[kb][r]);
          pa[kb * 4 + r] = f2bf(p);
        }

#pragma unroll
      for (int nb = 0; nb < 4; ++nb) {
        s16x8 vb =
            *(const s16x8*)(lds + 8192 + kbt * 2048 + (nb * 64 + lane) * 8);
        ctx[nb] = mfma_bf16(pa, vb, ctx[nb]);
      }
      // denominator: l[q-row] = P . 1 -- computed in the matrix pipe
      ctx5 = mfma_bf16(pa, vones, ctx5);
    }
    __syncthreads();
  }

  // epilogue: ctx row = q(quad*4+r), col = dh(l16); l = ctx5[r] (same lane!)
#pragma unroll
  for (int r = 0; r < 4; ++r) {
    float inv = 1.f / ctx5[r];
    int srow = qbase + quad * 4 + r;
#pragma unroll
    for (int nb = 0; nb < 4; ++nb) {
      int col = h * DH_ + nb * 16 + l16;
      ctx_out[(size_t)(b * S_ + srow) * D_ + col] = f2bf(ctx[nb][r] * inv);
    }
  }
}

// ---- final GEMM, staged 128x128 (R10-proven): out fp32 = ctx @ Wo^T + bo ---
__global__ __launch_bounds__(256) void gemm_final_kernel(
    const short* __restrict__ A, const short* __restrict__ Bt,
    const float* __restrict__ bias, float* __restrict__ out) {
  __shared__ short lds[8192];
  const int tid = threadIdx.x;
  const int lane = tid & 63;
  const int wave = tid >> 6;
  const int l16 = lane & 15;
  const int quad = lane >> 4;
  const int m0 = blockIdx.x * 128;
  const int n0 = blockIdx.y * 128;
  const int g = tid >> 6, c = tid & 63;
  const int r15 = c & 15, qd = c >> 4;

  f32x4 acc[4][4];
#pragma unroll
  for (int i = 0; i < 4; ++i)
#pragma unroll
    for (int j = 0; j < 4; ++j) acc[i][j] = (f32x4){0.f, 0.f, 0.f, 0.f};

  for (int k0 = 0; k0 < 1024; k0 += 32) {
    async16(A + (size_t)(m0 + g * 16 + r15) * 1024 + k0 + qd * 8, lds + tid * 8);
    async16(A + (size_t)(m0 + (g + 4) * 16 + r15) * 1024 + k0 + qd * 8,
            lds + 2048 + tid * 8);
    async16(Bt + (size_t)(n0 + g * 16 + r15) * 1024 + k0 + qd * 8,
            lds + 4096 + tid * 8);
    async16(Bt + (size_t)(n0 + (g + 4) * 16 + r15) * 1024 + k0 + qd * 8,
            lds + 6144 + tid * 8);
    __syncthreads();
    s16x8 a[4], b[4];
#pragma unroll
    for (int i = 0; i < 4; ++i)
      a[i] = *(const s16x8*)(lds + (((wave >> 1) * 4 + i) * 64 + lane) * 8);
#pragma unroll
    for (int j = 0; j < 4; ++j)
      b[j] = *(const s16x8*)(lds + 4096 + (((wave & 1) * 4 + j) * 64 + lane) * 8);
#pragma unroll
    for (int i = 0; i < 4; ++i)
#pragma unroll
      for (int j = 0; j < 4; ++j) acc[i][j] = mfma_bf16(a[i], b[j], acc[i][j]);
    __syncthreads();
  }

  const int mw = m0 + (wave >> 1) * 64;
  const int nw = n0 + (wave & 1) * 64;
#pragma unroll
  for (int i = 0; i < 4; ++i)
#pragma unroll
    for (int j = 0; j < 4; ++j)
#pragma unroll
      for (int r = 0; r < 4; ++r) {
        int m = mw + i * 16 + quad * 4 + r;
        int n = nw + j * 16 + l16;
        out[(size_t)m * 1024 + n] = acc[i][j][r] + bias[n];
      }
}

extern "C" void kernel_launch(void* const* d_in, const int* in_sizes, int n_in,
                              void* d_out, int out_size, void* d_ws,
                              size_t ws_size, hipStream_t stream) {
  const float* query = (const float*)d_in[0];
  const void* mask = d_in[1];
  const float* Wq = (const float*)d_in[2];
  const float* bq = (const float*)d_in[3];
  const float* Wk = (const float*)d_in[4];
  const float* bk = (const float*)d_in[5];
  const float* Wv = (const float*)d_in[6];
  const float* bv = (const float*)d_in[7];
  const float* Wo = (const float*)d_in[8];
  const float* bo = (const float*)d_in[9];

  const size_t NE = (size_t)B_ * S_ * D_;  // 4194304
  short* ws_s = (short*)d_ws;
  short* q_ws = ws_s;             // [B,H,S,DH] bf16 row-major (8 MB)
  short* KF = ws_s + NE;          // K fragment-order (8 MB)
  short* VF = ws_s + 2 * NE;      // V fragment-order, PV-permuted (8 MB)
  short* ctx_ws = ws_s + 3 * NE;  // [B,S,D] bf16 row-major (8 MB)
  short* wo_bf = ws_s;            // Wo bf16 (2 MB) -- aliases q_ws, written
                                  // only after attn (q_ws dead then)
  // scratch inside d_out (all dead before the final GEMM runs):
  short* qbf = (short*)d_out;          // [0:8M)  query bf16, fragment order
  short* wqkv = qbf + NE;              // [8:14M) Wq|Wk|Wv bf16, fragment order
  uint* bmT = (uint*)(wqkv + 3145728); // [14:15M) bitmask
  int* flag = (int*)(bmT + 262144);

  detect_mask_kernel<<<1, 64, 0, stream>>>((const uint*)mask, flag);
  build_bitmask_kernel<<<1024, 256, 0, stream>>>(mask, flag, bmT);
  convert_kernel<<<3584, 256, 0, stream>>>(query, Wq, Wk, Wv, qbf, wqkv);

  gemm_qkv_kernel<<<dim3(32, 24), 256, 0, stream>>>(qbf, wqkv, bq, bk, bv,
                                                    q_ws, KF, VF);

  attn_kernel<<<512, 512, 0, stream>>>(q_ws, KF, VF, bmT, ctx_ws);

  convert_wo_kernel<<<512, 256, 0, stream>>>(Wo, wo_bf);

  gemm_final_kernel<<<dim3(32, 8), 256, 0, stream>>>(ctx_ws, wo_bf, bo,
                                                     (float*)d_out);
}